// Round 1
// baseline (1173.154 us; speedup 1.0000x reference)
//
#include <hip/hip_runtime.h>

#define DIMC 128
#define NHEADS 4
#define HD 32
#define HID 256
#define BB 4
#define HH_ 128
#define WW_ 128
#define HW 16384
#define RS 16
#define STEP 14
#define NR 9
#define NREGB 81
#define NREG 324
#define TT 256

typedef unsigned short bfu;  // bf16 bits

__device__ __forceinline__ float bf2f(bfu u) {
  return __uint_as_float(((unsigned int)u) << 16);
}
__device__ __forceinline__ bfu f2bf(float f) {
  unsigned int i = __float_as_uint(f);
  unsigned int r = i + 0x7fffu + ((i >> 16) & 1u);
  return (bfu)(r >> 16);
}
__device__ __forceinline__ float gelu_exact(float x) {
  return 0.5f * x * (1.0f + erff(x * 0.70710678118654752f));
}
__device__ __forceinline__ void fma4x4(const float4 a, const float4 b, float acc[4][4]) {
  acc[0][0] = fmaf(b.x, a.x, acc[0][0]);
  acc[0][1] = fmaf(b.x, a.y, acc[0][1]);
  acc[0][2] = fmaf(b.x, a.z, acc[0][2]);
  acc[0][3] = fmaf(b.x, a.w, acc[0][3]);
  acc[1][0] = fmaf(b.y, a.x, acc[1][0]);
  acc[1][1] = fmaf(b.y, a.y, acc[1][1]);
  acc[1][2] = fmaf(b.y, a.z, acc[1][2]);
  acc[1][3] = fmaf(b.y, a.w, acc[1][3]);
  acc[2][0] = fmaf(b.z, a.x, acc[2][0]);
  acc[2][1] = fmaf(b.z, a.y, acc[2][1]);
  acc[2][2] = fmaf(b.z, a.z, acc[2][2]);
  acc[2][3] = fmaf(b.z, a.w, acc[2][3]);
  acc[3][0] = fmaf(b.w, a.x, acc[3][0]);
  acc[3][1] = fmaf(b.w, a.y, acc[3][1]);
  acc[3][2] = fmaf(b.w, a.z, acc[3][2]);
  acc[3][3] = fmaf(b.w, a.w, acc[3][3]);
}

// K1: gather regions -> tok [reg][c][t], per-token LN1 stats
__global__ __launch_bounds__(256) void k1_gather(
    const float* __restrict__ x, float* __restrict__ tok,
    float* __restrict__ mu1, float* __restrict__ rstd1) {
  int reg = blockIdx.x;
  int b = reg / NREGB, ij = reg % NREGB;
  int i = ij / NR, j = ij % NR;
  int t = threadIdx.x;
  int r = t >> 4, s = t & 15;
  int hh = i * STEP + r, ww = j * STEP + s;
  const float* xp = x + (size_t)b * DIMC * HW + (size_t)hh * WW_ + ww;
  float* tp = tok + (size_t)reg * DIMC * TT + t;
  float sum = 0.f, sq = 0.f;
  #pragma unroll 4
  for (int c = 0; c < DIMC; ++c) {
    float v = xp[(size_t)c * HW];
    tp[c * TT] = v;
    sum += v;
    sq = fmaf(v, v, sq);
  }
  float mu = sum * (1.0f / DIMC);
  float var = sq * (1.0f / DIMC) - mu * mu;
  mu1[reg * TT + t] = mu;
  rstd1[reg * TT + t] = rsqrtf(var + 1e-5f);
}

// K2: qkv = LN1(tok) @ w_qkv  -> bf16 [reg][j(384)][t]
__global__ __launch_bounds__(256) void k2_qkv(
    const float* __restrict__ tok, const float* __restrict__ mu1,
    const float* __restrict__ rstd1, const float* __restrict__ g,
    const float* __restrict__ bia, const float* __restrict__ wqkv,
    bfu* __restrict__ qkv) {
  int reg = blockIdx.x;
  int jt = blockIdx.y >> 2;  // 0..5
  int tt = blockIdx.y & 3;   // 0..3
  __shared__ float As[128 * 64];
  __shared__ float Bs[128 * 64];
  int tid = threadIdx.x;
  const float* tokr = tok + (size_t)reg * DIMC * TT;
  for (int idx = tid; idx < 8192; idx += 256) {
    int c = idx >> 6, l = idx & 63;
    int t = tt * 64 + l;
    float v = tokr[c * TT + t];
    As[idx] = (v - mu1[reg * TT + t]) * rstd1[reg * TT + t] * g[c] + bia[c];
    Bs[idx] = wqkv[c * 384 + jt * 64 + l];
  }
  __syncthreads();
  int ti = tid & 15, tj = tid >> 4;
  float acc[4][4] = {};
  #pragma unroll 8
  for (int k = 0; k < 128; ++k) {
    float4 a = *(const float4*)&As[k * 64 + ti * 4];
    float4 bb = *(const float4*)&Bs[k * 64 + tj * 4];
    fma4x4(a, bb, acc);
  }
  bfu* outp = qkv + (size_t)reg * 384 * TT;
  #pragma unroll
  for (int jj = 0; jj < 4; ++jj) {
    int j = jt * 64 + tj * 4 + jj;
    ushort4 pk;
    pk.x = f2bf(acc[jj][0]);
    pk.y = f2bf(acc[jj][1]);
    pk.z = f2bf(acc[jj][2]);
    pk.w = f2bf(acc[jj][3]);
    *(ushort4*)&outp[j * TT + tt * 64 + ti * 4] = pk;
  }
}

// K3: per (region, head) attention. 128 threads, 2 q-rows/thread.
// k/v staged fp32 in LDS packed [d/4][j][4] for float4 broadcast reads.
__global__ __launch_bounds__(128) void k3_attn(
    const bfu* __restrict__ qkv, bfu* __restrict__ o) {
  int reg = blockIdx.x;
  int h = blockIdx.y;
  __shared__ float smem[16384];  // 64 KB: k at [0,8192), v at [8192,16384)
  int tid = threadIdx.x;
  const bfu* base = qkv + (size_t)reg * 384 * TT;
  for (int idx = tid; idx < 8192; idx += 128) {
    int d = idx >> 8, j = idx & 255;
    int slot = (d >> 2) * 1024 + j * 4 + (d & 3);
    smem[slot] = bf2f(base[(128 + h * HD + d) * TT + j]);
    smem[8192 + slot] = bf2f(base[(256 + h * HD + d) * TT + j]);
  }
  const float scale = 0.17677669529663687f;  // 1/sqrt(32)
  float q0[32], q1[32];
  #pragma unroll
  for (int d = 0; d < 32; ++d) {
    q0[d] = bf2f(base[(h * HD + d) * TT + tid]) * scale;
    q1[d] = bf2f(base[(h * HD + d) * TT + tid + 128]) * scale;
  }
  __syncthreads();
  const float4* k4 = (const float4*)smem;
  const float4* v4 = (const float4*)(smem + 8192);
  float m0 = -1e30f, l0 = 0.f, m1 = -1e30f, l1 = 0.f;
  float acc0[32] = {}, acc1[32] = {};
  for (int j = 0; j < 256; ++j) {
    float4 kk[8], vv[8];
    #pragma unroll
    for (int gg = 0; gg < 8; ++gg) kk[gg] = k4[gg * 256 + j];
    #pragma unroll
    for (int gg = 0; gg < 8; ++gg) vv[gg] = v4[gg * 256 + j];
    float s0 = 0.f, s1 = 0.f;
    #pragma unroll
    for (int gg = 0; gg < 8; ++gg) {
      s0 = fmaf(q0[4 * gg + 0], kk[gg].x, s0);
      s0 = fmaf(q0[4 * gg + 1], kk[gg].y, s0);
      s0 = fmaf(q0[4 * gg + 2], kk[gg].z, s0);
      s0 = fmaf(q0[4 * gg + 3], kk[gg].w, s0);
      s1 = fmaf(q1[4 * gg + 0], kk[gg].x, s1);
      s1 = fmaf(q1[4 * gg + 1], kk[gg].y, s1);
      s1 = fmaf(q1[4 * gg + 2], kk[gg].z, s1);
      s1 = fmaf(q1[4 * gg + 3], kk[gg].w, s1);
    }
    if (s0 <= m0) {
      float p = __expf(s0 - m0);
      l0 += p;
      #pragma unroll
      for (int gg = 0; gg < 8; ++gg) {
        acc0[4 * gg + 0] = fmaf(p, vv[gg].x, acc0[4 * gg + 0]);
        acc0[4 * gg + 1] = fmaf(p, vv[gg].y, acc0[4 * gg + 1]);
        acc0[4 * gg + 2] = fmaf(p, vv[gg].z, acc0[4 * gg + 2]);
        acc0[4 * gg + 3] = fmaf(p, vv[gg].w, acc0[4 * gg + 3]);
      }
    } else {
      float f = __expf(m0 - s0);
      l0 = fmaf(l0, f, 1.0f);
      #pragma unroll
      for (int gg = 0; gg < 8; ++gg) {
        acc0[4 * gg + 0] = fmaf(acc0[4 * gg + 0], f, vv[gg].x);
        acc0[4 * gg + 1] = fmaf(acc0[4 * gg + 1], f, vv[gg].y);
        acc0[4 * gg + 2] = fmaf(acc0[4 * gg + 2], f, vv[gg].z);
        acc0[4 * gg + 3] = fmaf(acc0[4 * gg + 3], f, vv[gg].w);
      }
      m0 = s0;
    }
    if (s1 <= m1) {
      float p = __expf(s1 - m1);
      l1 += p;
      #pragma unroll
      for (int gg = 0; gg < 8; ++gg) {
        acc1[4 * gg + 0] = fmaf(p, vv[gg].x, acc1[4 * gg + 0]);
        acc1[4 * gg + 1] = fmaf(p, vv[gg].y, acc1[4 * gg + 1]);
        acc1[4 * gg + 2] = fmaf(p, vv[gg].z, acc1[4 * gg + 2]);
        acc1[4 * gg + 3] = fmaf(p, vv[gg].w, acc1[4 * gg + 3]);
      }
    } else {
      float f = __expf(m1 - s1);
      l1 = fmaf(l1, f, 1.0f);
      #pragma unroll
      for (int gg = 0; gg < 8; ++gg) {
        acc1[4 * gg + 0] = fmaf(acc1[4 * gg + 0], f, vv[gg].x);
        acc1[4 * gg + 1] = fmaf(acc1[4 * gg + 1], f, vv[gg].y);
        acc1[4 * gg + 2] = fmaf(acc1[4 * gg + 2], f, vv[gg].z);
        acc1[4 * gg + 3] = fmaf(acc1[4 * gg + 3], f, vv[gg].w);
      }
      m1 = s1;
    }
  }
  __syncthreads();
  // stage o rows transposed for coalesced global write: smem[t*33 + d]
  float inv0 = 1.0f / l0, inv1 = 1.0f / l1;
  #pragma unroll
  for (int d = 0; d < 32; ++d) {
    smem[tid * 33 + d] = acc0[d] * inv0;
    smem[(tid + 128) * 33 + d] = acc1[d] * inv1;
  }
  __syncthreads();
  bfu* ob = o + (size_t)reg * DIMC * TT;
  for (int idx = tid; idx < 8192; idx += 128) {
    int d = idx >> 8, t = idx & 255;
    ob[(h * HD + d) * TT + t] = f2bf(smem[t * 33 + d]);
  }
}

// K4: tok = o @ w_out + b_out + tok  (in place)
__global__ __launch_bounds__(256) void k4_outproj(
    const bfu* __restrict__ o, const float* __restrict__ wout,
    const float* __restrict__ bout, float* __restrict__ tok) {
  int reg = blockIdx.x;
  int ct = blockIdx.y >> 2, tt = blockIdx.y & 3;
  __shared__ float As[128 * 64];
  __shared__ float Bs[128 * 64];
  int tid = threadIdx.x;
  const bfu* ob = o + (size_t)reg * DIMC * TT;
  for (int idx = tid; idx < 8192; idx += 256) {
    int k = idx >> 6, l = idx & 63;
    As[idx] = bf2f(ob[k * TT + tt * 64 + l]);
    Bs[idx] = wout[k * 128 + ct * 64 + l];
  }
  __syncthreads();
  int ti = tid & 15, tj = tid >> 4;
  float acc[4][4] = {};
  #pragma unroll 8
  for (int k = 0; k < 128; ++k) {
    float4 a = *(const float4*)&As[k * 64 + ti * 4];
    float4 bb = *(const float4*)&Bs[k * 64 + tj * 4];
    fma4x4(a, bb, acc);
  }
  float* tokr = tok + (size_t)reg * DIMC * TT;
  #pragma unroll
  for (int jj = 0; jj < 4; ++jj) {
    int c = ct * 64 + tj * 4 + jj;
    float bo = bout[c];
    float4 res = *(const float4*)&tokr[c * TT + tt * 64 + ti * 4];
    res.x += acc[jj][0] + bo;
    res.y += acc[jj][1] + bo;
    res.z += acc[jj][2] + bo;
    res.w += acc[jj][3] + bo;
    *(float4*)&tokr[c * TT + tt * 64 + ti * 4] = res;
  }
}

// K5: overlap-average merge -> xf NCHW
__global__ __launch_bounds__(128) void k5_merge(
    const float* __restrict__ tok, float* __restrict__ xf) {
  int hh = blockIdx.x, c = blockIdx.y, b = blockIdx.z;
  int w = threadIdx.x;
  int ilo = (hh >= 2) ? (hh - 2) / 14 : 0;
  int ihi = hh / 14;
  if (ihi > 8) ihi = 8;
  int jlo = (w >= 2) ? (w - 2) / 14 : 0;
  int jhi = w / 14;
  if (jhi > 8) jhi = 8;
  float sum = 0.f;
  for (int i = ilo; i <= ihi; ++i)
    for (int j = jlo; j <= jhi; ++j) {
      int reg = b * NREGB + i * NR + j;
      int r = hh - i * STEP, s = w - j * STEP;
      sum += tok[(size_t)reg * DIMC * TT + c * TT + r * 16 + s];
    }
  float cnt = (float)((ihi - ilo + 1) * (jhi - jlo + 1));
  xf[((size_t)(b * DIMC + c) << 14) + hh * WW_ + w] = sum / cnt;
}

// K5b: LN2 per-pixel stats
__global__ __launch_bounds__(256) void k5b_ln2stats(
    const float* __restrict__ xf, float* __restrict__ mu2,
    float* __restrict__ rstd2) {
  int pg = blockIdx.x * 256 + threadIdx.x;  // 0..65535
  int b = pg >> 14, p = pg & 16383;
  const float* xp = xf + ((size_t)b * DIMC << 14) + p;
  float sum = 0.f, sq = 0.f;
  #pragma unroll 4
  for (int c = 0; c < DIMC; ++c) {
    float v = xp[(size_t)c << 14];
    sum += v;
    sq = fmaf(v, v, sq);
  }
  float mu = sum * (1.0f / DIMC);
  float var = sq * (1.0f / DIMC) - mu * mu;
  mu2[pg] = mu;
  rstd2[pg] = rsqrtf(var + 1e-5f);
}

// K6: ym = LN2(xf) @ w_p0 + b_p0 -> bf16 [b][f][p]
__global__ __launch_bounds__(256) void k6_p0(
    const float* __restrict__ xf, const float* __restrict__ mu2,
    const float* __restrict__ rstd2, const float* __restrict__ g,
    const float* __restrict__ bia, const float* __restrict__ wp0,
    const float* __restrict__ bp0, bfu* __restrict__ ym) {
  int pt = blockIdx.x, ft = blockIdx.y, b = blockIdx.z;
  __shared__ float As[128 * 64];
  __shared__ float Bs[128 * 64];
  int tid = threadIdx.x;
  for (int idx = tid; idx < 8192; idx += 256) {
    int c = idx >> 6, l = idx & 63;
    int p = pt * 64 + l;
    float v = xf[((size_t)(b * DIMC + c) << 14) + p];
    As[idx] = (v - mu2[(b << 14) + p]) * rstd2[(b << 14) + p] * g[c] + bia[c];
    Bs[idx] = wp0[c * HID + ft * 64 + l];
  }
  __syncthreads();
  int ti = tid & 15, tj = tid >> 4;
  float acc[4][4] = {};
  #pragma unroll 8
  for (int k = 0; k < 128; ++k) {
    float4 a = *(const float4*)&As[k * 64 + ti * 4];
    float4 bb = *(const float4*)&Bs[k * 64 + tj * 4];
    fma4x4(a, bb, acc);
  }
  #pragma unroll
  for (int jj = 0; jj < 4; ++jj) {
    int f = ft * 64 + tj * 4 + jj;
    float bo = bp0[f];
    ushort4 pk;
    pk.x = f2bf(acc[jj][0] + bo);
    pk.y = f2bf(acc[jj][1] + bo);
    pk.z = f2bf(acc[jj][2] + bo);
    pk.w = f2bf(acc[jj][3] + bo);
    *(ushort4*)&ym[((size_t)(b * HID + f) << 14) + pt * 64 + ti * 4] = pk;
  }
}

// K7: 5x5 depthwise conv, pad 2
__global__ __launch_bounds__(128) void k7_conv(
    const bfu* __restrict__ ym, const float* __restrict__ dwk,
    bfu* __restrict__ ym2) {
  int hh = blockIdx.x, f = blockIdx.y, b = blockIdx.z;
  int w = threadIdx.x;
  const bfu* in = ym + ((size_t)(b * HID + f) << 14);
  const float* wk = dwk + f * 25;
  float acc = 0.f;
  #pragma unroll
  for (int ky = 0; ky < 5; ++ky) {
    int y = hh + ky - 2;
    if (y < 0 || y >= 128) continue;
    #pragma unroll
    for (int kx = 0; kx < 5; ++kx) {
      int xx = w + kx - 2;
      if (xx < 0 || xx >= 128) continue;
      acc = fmaf(bf2f(in[y * 128 + xx]), wk[ky * 5 + kx], acc);
    }
  }
  ym2[((size_t)(b * HID + f) << 14) + hh * 128 + w] = f2bf(acc);
}

// K8: BN batch stats per channel (one block per channel)
__global__ __launch_bounds__(256) void k8_bnstats(
    const bfu* __restrict__ ym2, float* __restrict__ bnm,
    float* __restrict__ bnr) {
  int f = blockIdx.x;
  int tid = threadIdx.x;
  float sum = 0.f, sq = 0.f;
  for (int b = 0; b < BB; ++b) {
    const bfu* p = ym2 + ((size_t)(b * HID + f) << 14);
    for (int idx = tid; idx < HW; idx += 256) {
      float v = bf2f(p[idx]);
      sum += v;
      sq = fmaf(v, v, sq);
    }
  }
  __shared__ float rs[256];
  __shared__ float rq[256];
  rs[tid] = sum;
  rq[tid] = sq;
  __syncthreads();
  for (int off = 128; off > 0; off >>= 1) {
    if (tid < off) {
      rs[tid] += rs[tid + off];
      rq[tid] += rq[tid + off];
    }
    __syncthreads();
  }
  if (tid == 0) {
    float mu = rs[0] * (1.0f / 65536.f);
    float var = rq[0] * (1.0f / 65536.f) - mu * mu;
    bnm[f] = mu;
    bnr[f] = rsqrtf(var + 1e-5f);
  }
}

// K9: g2 = gelu(gelu(bn(ym2)))  (writes into ym buffer)
__global__ __launch_bounds__(256) void k9_act(
    const bfu* __restrict__ ym2, const float* __restrict__ bnm,
    const float* __restrict__ bnr, const float* __restrict__ g,
    const float* __restrict__ bia, bfu* __restrict__ g2) {
  int base = (blockIdx.x * 256 + threadIdx.x) * 4;
  int f = (base >> 14) & (HID - 1);
  float mean = bnm[f];
  float sc = bnr[f] * g[f];
  float bb = bia[f];
  ushort4 rv = *(const ushort4*)&ym2[base];
  float v0 = (bf2f(rv.x) - mean) * sc + bb;
  float v1 = (bf2f(rv.y) - mean) * sc + bb;
  float v2 = (bf2f(rv.z) - mean) * sc + bb;
  float v3 = (bf2f(rv.w) - mean) * sc + bb;
  v0 = gelu_exact(gelu_exact(v0));
  v1 = gelu_exact(gelu_exact(v1));
  v2 = gelu_exact(gelu_exact(v2));
  v3 = gelu_exact(gelu_exact(v3));
  ushort4 pk;
  pk.x = f2bf(v0);
  pk.y = f2bf(v1);
  pk.z = f2bf(v2);
  pk.w = f2bf(v3);
  *(ushort4*)&g2[base] = pk;
}

// K10: out = g2 @ w_p2 + b_p2 + xf  (fp32 out, NCHW)
__global__ __launch_bounds__(256) void k10_p2(
    const bfu* __restrict__ g2, const float* __restrict__ wp2,
    const float* __restrict__ bp2, const float* __restrict__ xf,
    float* __restrict__ outp) {
  int pt = blockIdx.x, ct = blockIdx.y, b = blockIdx.z;
  __shared__ float As[128 * 64];
  __shared__ float Bs[128 * 64];
  int tid = threadIdx.x;
  int ti = tid & 15, tj = tid >> 4;
  float acc[4][4] = {};
  for (int kt = 0; kt < 2; ++kt) {
    for (int idx = tid; idx < 8192; idx += 256) {
      int k = idx >> 6, l = idx & 63;
      int f = kt * 128 + k;
      As[idx] = bf2f(g2[((size_t)(b * HID + f) << 14) + pt * 64 + l]);
      Bs[idx] = wp2[f * DIMC + ct * 64 + l];
    }
    __syncthreads();
    #pragma unroll 8
    for (int k = 0; k < 128; ++k) {
      float4 a = *(const float4*)&As[k * 64 + ti * 4];
      float4 bb = *(const float4*)&Bs[k * 64 + tj * 4];
      fma4x4(a, bb, acc);
    }
    __syncthreads();
  }
  #pragma unroll
  for (int jj = 0; jj < 4; ++jj) {
    int c = ct * 64 + tj * 4 + jj;
    float bo = bp2[c];
    size_t off = ((size_t)(b * DIMC + c) << 14) + pt * 64 + ti * 4;
    float4 res = *(const float4*)&xf[off];
    res.x += acc[jj][0] + bo;
    res.y += acc[jj][1] + bo;
    res.z += acc[jj][2] + bo;
    res.w += acc[jj][3] + bo;
    *(float4*)&outp[off] = res;
  }
}

extern "C" void kernel_launch(void* const* d_in, const int* in_sizes, int n_in,
                              void* d_out, int out_size, void* d_ws,
                              size_t ws_size, hipStream_t stream) {
  const float* x = (const float*)d_in[0];
  const float* ln1_g = (const float*)d_in[1];
  const float* ln1_b = (const float*)d_in[2];
  const float* w_qkv = (const float*)d_in[3];
  const float* w_out = (const float*)d_in[4];
  const float* b_out = (const float*)d_in[5];
  const float* ln2_g = (const float*)d_in[6];
  const float* ln2_b = (const float*)d_in[7];
  const float* w_p0 = (const float*)d_in[8];
  const float* b_p0 = (const float*)d_in[9];
  const float* dw_k = (const float*)d_in[10];
  const float* bn_g = (const float*)d_in[11];
  const float* bn_b = (const float*)d_in[12];
  const float* w_p2 = (const float*)d_in[13];
  const float* b_p2 = (const float*)d_in[14];
  float* outp = (float*)d_out;

  char* ws = (char*)d_ws;
  size_t off = 0;
  auto alloc = [&](size_t bytes) {
    void* p = ws + off;
    off += (bytes + 1023) & ~(size_t)1023;
    return p;
  };
  float* tok = (float*)alloc((size_t)NREG * DIMC * TT * 4);
  float* mu1 = (float*)alloc((size_t)NREG * TT * 4);
  float* rstd1 = (float*)alloc((size_t)NREG * TT * 4);
  bfu* qkv = (bfu*)alloc((size_t)NREG * 384 * TT * 2);
  bfu* o = (bfu*)alloc((size_t)NREG * DIMC * TT * 2);
  float* xf = (float*)alloc((size_t)BB * DIMC * HW * 4);
  float* mu2 = (float*)alloc((size_t)BB * HW * 4);
  float* rstd2 = (float*)alloc((size_t)BB * HW * 4);
  bfu* ym = (bfu*)alloc((size_t)BB * HID * HW * 2);
  bfu* ym2 = (bfu*)alloc((size_t)BB * HID * HW * 2);
  float* bnm = (float*)alloc(HID * 4);
  float* bnr = (float*)alloc(HID * 4);

  k1_gather<<<NREG, 256, 0, stream>>>(x, tok, mu1, rstd1);
  k2_qkv<<<dim3(NREG, 24), 256, 0, stream>>>(tok, mu1, rstd1, ln1_g, ln1_b,
                                             w_qkv, qkv);
  k3_attn<<<dim3(NREG, NHEADS), 128, 0, stream>>>(qkv, o);
  k4_outproj<<<dim3(NREG, 8), 256, 0, stream>>>(o, w_out, b_out, tok);
  k5_merge<<<dim3(HH_, DIMC, BB), 128, 0, stream>>>(tok, xf);
  k5b_ln2stats<<<256, 256, 0, stream>>>(xf, mu2, rstd2);
  k6_p0<<<dim3(256, 4, BB), 256, 0, stream>>>(xf, mu2, rstd2, ln2_g, ln2_b,
                                              w_p0, b_p0, ym);
  k7_conv<<<dim3(HH_, HID, BB), 128, 0, stream>>>(ym, dw_k, ym2);
  k8_bnstats<<<HID, 256, 0, stream>>>(ym2, bnm, bnr);
  k9_act<<<16384, 256, 0, stream>>>(ym2, bnm, bnr, bn_g, bn_b, ym);
  k10_p2<<<dim3(256, 2, BB), 256, 0, stream>>>(ym, w_p2, b_p2, xf, outp);
}

// Round 2
// 870.170 us; speedup vs baseline: 1.3482x; 1.3482x over previous
//
#include <hip/hip_runtime.h>

#define DIMC 128
#define NHEADS 4
#define HD 32
#define HID 256
#define BB 4
#define HH_ 128
#define WW_ 128
#define HW 16384
#define RS 16
#define STEP 14
#define NR 9
#define NREGB 81
#define NREG 324
#define TT 256

typedef unsigned short bfu;  // bf16 bits
typedef __attribute__((ext_vector_type(8))) short bf16x8;
typedef __attribute__((ext_vector_type(4))) float f32x4;

__device__ __forceinline__ float bf2f(bfu u) {
  return __uint_as_float(((unsigned int)u) << 16);
}
__device__ __forceinline__ bfu f2bf(float f) {
  unsigned int i = __float_as_uint(f);
  unsigned int r = i + 0x7fffu + ((i >> 16) & 1u);
  return (bfu)(r >> 16);
}
__device__ __forceinline__ float gelu_exact(float x) {
  return 0.5f * x * (1.0f + erff(x * 0.70710678118654752f));
}
__device__ __forceinline__ void fma4x4(const float4 a, const float4 b, float acc[4][4]) {
  acc[0][0] = fmaf(b.x, a.x, acc[0][0]);
  acc[0][1] = fmaf(b.x, a.y, acc[0][1]);
  acc[0][2] = fmaf(b.x, a.z, acc[0][2]);
  acc[0][3] = fmaf(b.x, a.w, acc[0][3]);
  acc[1][0] = fmaf(b.y, a.x, acc[1][0]);
  acc[1][1] = fmaf(b.y, a.y, acc[1][1]);
  acc[1][2] = fmaf(b.y, a.z, acc[1][2]);
  acc[1][3] = fmaf(b.y, a.w, acc[1][3]);
  acc[2][0] = fmaf(b.z, a.x, acc[2][0]);
  acc[2][1] = fmaf(b.z, a.y, acc[2][1]);
  acc[2][2] = fmaf(b.z, a.z, acc[2][2]);
  acc[2][3] = fmaf(b.z, a.w, acc[2][3]);
  acc[3][0] = fmaf(b.w, a.x, acc[3][0]);
  acc[3][1] = fmaf(b.w, a.y, acc[3][1]);
  acc[3][2] = fmaf(b.w, a.z, acc[3][2]);
  acc[3][3] = fmaf(b.w, a.w, acc[3][3]);
}

// K1: gather regions -> tok [reg][c][t], per-token LN1 stats
__global__ __launch_bounds__(256) void k1_gather(
    const float* __restrict__ x, float* __restrict__ tok,
    float* __restrict__ mu1, float* __restrict__ rstd1) {
  int reg = blockIdx.x;
  int b = reg / NREGB, ij = reg % NREGB;
  int i = ij / NR, j = ij % NR;
  int t = threadIdx.x;
  int r = t >> 4, s = t & 15;
  int hh = i * STEP + r, ww = j * STEP + s;
  const float* xp = x + (size_t)b * DIMC * HW + (size_t)hh * WW_ + ww;
  float* tp = tok + (size_t)reg * DIMC * TT + t;
  float sum = 0.f, sq = 0.f;
  #pragma unroll 4
  for (int c = 0; c < DIMC; ++c) {
    float v = xp[(size_t)c * HW];
    tp[c * TT] = v;
    sum += v;
    sq = fmaf(v, v, sq);
  }
  float mu = sum * (1.0f / DIMC);
  float var = sq * (1.0f / DIMC) - mu * mu;
  mu1[reg * TT + t] = mu;
  rstd1[reg * TT + t] = rsqrtf(var + 1e-5f);
}

// K2: qkvt = LN1(tok) @ w_qkv -> bf16 TOKEN-major [reg][t(256)][j(384)]
__global__ __launch_bounds__(256) void k2_qkv(
    const float* __restrict__ tok, const float* __restrict__ mu1,
    const float* __restrict__ rstd1, const float* __restrict__ g,
    const float* __restrict__ bia, const float* __restrict__ wqkv,
    bfu* __restrict__ qkvt) {
  int reg = blockIdx.x;
  int jt = blockIdx.y >> 2;  // 0..5
  int tt = blockIdx.y & 3;   // 0..3
  __shared__ float As[128 * 64];
  __shared__ float Bs[128 * 64];
  int tid = threadIdx.x;
  const float* tokr = tok + (size_t)reg * DIMC * TT;
  for (int idx = tid; idx < 8192; idx += 256) {
    int c = idx >> 6, l = idx & 63;
    int t = tt * 64 + l;
    float v = tokr[c * TT + t];
    As[idx] = (v - mu1[reg * TT + t]) * rstd1[reg * TT + t] * g[c] + bia[c];
    Bs[idx] = wqkv[c * 384 + jt * 64 + l];
  }
  __syncthreads();
  int ti = tid & 15, tj = tid >> 4;
  float acc[4][4] = {};  // acc[t-local][j-local]
  #pragma unroll 8
  for (int k = 0; k < 128; ++k) {
    float4 a = *(const float4*)&Bs[k * 64 + ti * 4];  // j-vec
    float4 bb = *(const float4*)&As[k * 64 + tj * 4]; // t-vec
    fma4x4(a, bb, acc);
  }
  bfu* outp = qkvt + (size_t)reg * 384 * TT;
  #pragma unroll
  for (int r = 0; r < 4; ++r) {
    int t = tt * 64 + tj * 4 + r;
    ushort4 pk;
    pk.x = f2bf(acc[r][0]);
    pk.y = f2bf(acc[r][1]);
    pk.z = f2bf(acc[r][2]);
    pk.w = f2bf(acc[r][3]);
    *(ushort4*)&outp[t * 384 + jt * 64 + ti * 4] = pk;
  }
}

// K3: MFMA attention. One block per (region, head), 4 waves, each wave does
// 4 q-tiles of 16 rows. Q/K frags direct from global (token-major), V^T in
// LDS, P via per-wave LDS round-trip (C/D -> A layout). o token-major.
__global__ __launch_bounds__(256, 2) void k3_attn(
    const bfu* __restrict__ qkvt, bfu* __restrict__ o) {
  int reg = blockIdx.x;
  int h = blockIdx.y;
  __shared__ __align__(16) bfu sVt[32 * 264];
  __shared__ __align__(16) bfu sP[4][16 * 264];
  int tid = threadIdx.x;
  int wave = tid >> 6, lane = tid & 63;
  int quad = lane >> 4, n16 = lane & 15;
  const bfu* qb = qkvt + (size_t)reg * 256 * 384;
  // stage V^T: [dim 32][tok 256] stride 264
  {
    const bfu* vrow = qb + tid * 384 + 256 + h * 32;
    #pragma unroll
    for (int dg = 0; dg < 8; ++dg) {
      ushort4 v4 = *(const ushort4*)(vrow + dg * 4);
      sVt[(dg * 4 + 0) * 264 + tid] = v4.x;
      sVt[(dg * 4 + 1) * 264 + tid] = v4.y;
      sVt[(dg * 4 + 2) * 264 + tid] = v4.z;
      sVt[(dg * 4 + 3) * 264 + tid] = v4.w;
    }
  }
  __syncthreads();
  // preload V B-frags (persist whole kernel): vf[nt][kt]
  bf16x8 vf[2][8];
  #pragma unroll
  for (int nt = 0; nt < 2; ++nt)
    #pragma unroll
    for (int kt = 0; kt < 8; ++kt)
      vf[nt][kt] = *(const bf16x8*)&sVt[(nt * 16 + n16) * 264 + kt * 32 + quad * 8];
  const bfu* kptr = qb + n16 * 384 + 128 + h * 32 + quad * 8;
  const f32x4 zero = {0.f, 0.f, 0.f, 0.f};
  const float scale = 0.17677669529663687f;  // 1/sqrt(32)
  bfu* pw = sP[wave];
  for (int mi = 0; mi < 4; ++mi) {
    int mt = wave * 4 + mi;
    bf16x8 qf = *(const bf16x8*)(qb + (mt * 16 + n16) * 384 + h * 32 + quad * 8);
    f32x4 st[16];
    #pragma unroll
    for (int T = 0; T < 16; ++T) {
      bf16x8 kf = *(const bf16x8*)(kptr + T * 16 * 384);
      st[T] = __builtin_amdgcn_mfma_f32_16x16x32_bf16(qf, kf, zero, 0, 0, 0);
    }
    // softmax: lane's rows are quad*4+r, cols T*16 + n16 spread over 16 lanes
    float inv[4];
    #pragma unroll
    for (int r = 0; r < 4; ++r) {
      float m = st[0][r];
      #pragma unroll
      for (int T = 1; T < 16; ++T) m = fmaxf(m, st[T][r]);
      #pragma unroll
      for (int mk = 1; mk < 16; mk <<= 1) m = fmaxf(m, __shfl_xor(m, mk, 64));
      float l = 0.f;
      #pragma unroll
      for (int T = 0; T < 16; ++T) {
        float p = __expf((st[T][r] - m) * scale);
        st[T][r] = p;
        l += p;
      }
      #pragma unroll
      for (int mk = 1; mk < 16; mk <<= 1) l += __shfl_xor(l, mk, 64);
      inv[r] = 1.0f / l;
    }
    // P (bf16) -> per-wave LDS [16][264] for layout transform
    #pragma unroll
    for (int T = 0; T < 16; ++T) {
      #pragma unroll
      for (int r = 0; r < 4; ++r)
        pw[(quad * 4 + r) * 264 + T * 16 + n16] = f2bf(st[T][r]);
    }
    __builtin_amdgcn_wave_barrier();
    f32x4 oa0 = zero, oa1 = zero;
    #pragma unroll
    for (int kt = 0; kt < 8; ++kt) {
      bf16x8 pf = *(const bf16x8*)&pw[n16 * 264 + kt * 32 + quad * 8];
      oa0 = __builtin_amdgcn_mfma_f32_16x16x32_bf16(pf, vf[0][kt], oa0, 0, 0, 0);
      oa1 = __builtin_amdgcn_mfma_f32_16x16x32_bf16(pf, vf[1][kt], oa1, 0, 0, 0);
    }
    __builtin_amdgcn_wave_barrier();
    bfu* ob = o + ((size_t)reg * 256 + mt * 16 + quad * 4) * 128 + h * 32 + n16;
    #pragma unroll
    for (int r = 0; r < 4; ++r) {
      ob[r * 128] = f2bf(oa0[r] * inv[r]);
      ob[r * 128 + 16] = f2bf(oa1[r] * inv[r]);
    }
  }
}

// K4: tok[c][t] += o @ w_out + b_out.  o is token-major -> transpose-stage
// into padded LDS (stride 68, 16B-aligned float4 rows), two 64-k phases.
__global__ __launch_bounds__(256) void k4_outproj(
    const bfu* __restrict__ o, const float* __restrict__ wout,
    const float* __restrict__ bout, float* __restrict__ tok) {
  int reg = blockIdx.x;
  int ct = blockIdx.y >> 2, tt = blockIdx.y & 3;
  __shared__ float As[128 * 64];  // wout [k][c64]
  __shared__ float Bs[64 * 68];   // o^T  [k64][t64] padded
  int tid = threadIdx.x;
  for (int idx = tid; idx < 8192; idx += 256) {
    int k = idx >> 6, l = idx & 63;
    As[idx] = wout[k * 128 + ct * 64 + l];
  }
  int ti = tid & 15, tj = tid >> 4;
  float acc[4][4] = {};  // acc[c-local][t-local]
  const bfu* ob = o + (size_t)reg * 256 * 128;
  for (int ph = 0; ph < 2; ++ph) {
    __syncthreads();
    for (int idx = tid; idx < 4096; idx += 256) {
      int l = idx >> 6, k = idx & 63;
      Bs[k * 68 + l] = bf2f(ob[(tt * 64 + l) * 128 + ph * 64 + k]);
    }
    __syncthreads();
    #pragma unroll 8
    for (int k = 0; k < 64; ++k) {
      float4 a = *(const float4*)&Bs[k * 68 + ti * 4];            // t-vec
      float4 bb = *(const float4*)&As[(ph * 64 + k) * 64 + tj * 4];  // c-vec
      fma4x4(a, bb, acc);
    }
  }
  float* tokr = tok + (size_t)reg * DIMC * TT;
  #pragma unroll
  for (int jj = 0; jj < 4; ++jj) {
    int c = ct * 64 + tj * 4 + jj;
    float bo = bout[c];
    float4 res = *(const float4*)&tokr[c * TT + tt * 64 + ti * 4];
    res.x += acc[jj][0] + bo;
    res.y += acc[jj][1] + bo;
    res.z += acc[jj][2] + bo;
    res.w += acc[jj][3] + bo;
    *(float4*)&tokr[c * TT + tt * 64 + ti * 4] = res;
  }
}

// K5: overlap-average merge -> xf NCHW
__global__ __launch_bounds__(128) void k5_merge(
    const float* __restrict__ tok, float* __restrict__ xf) {
  int hh = blockIdx.x, c = blockIdx.y, b = blockIdx.z;
  int w = threadIdx.x;
  int ilo = (hh >= 2) ? (hh - 2) / 14 : 0;
  int ihi = hh / 14;
  if (ihi > 8) ihi = 8;
  int jlo = (w >= 2) ? (w - 2) / 14 : 0;
  int jhi = w / 14;
  if (jhi > 8) jhi = 8;
  float sum = 0.f;
  for (int i = ilo; i <= ihi; ++i)
    for (int j = jlo; j <= jhi; ++j) {
      int reg = b * NREGB + i * NR + j;
      int r = hh - i * STEP, s = w - j * STEP;
      sum += tok[(size_t)reg * DIMC * TT + c * TT + r * 16 + s];
    }
  float cnt = (float)((ihi - ilo + 1) * (jhi - jlo + 1));
  xf[((size_t)(b * DIMC + c) << 14) + hh * WW_ + w] = sum / cnt;
}

// K5b: LN2 per-pixel stats
__global__ __launch_bounds__(256) void k5b_ln2stats(
    const float* __restrict__ xf, float* __restrict__ mu2,
    float* __restrict__ rstd2) {
  int pg = blockIdx.x * 256 + threadIdx.x;  // 0..65535
  int b = pg >> 14, p = pg & 16383;
  const float* xp = xf + ((size_t)b * DIMC << 14) + p;
  float sum = 0.f, sq = 0.f;
  #pragma unroll 4
  for (int c = 0; c < DIMC; ++c) {
    float v = xp[(size_t)c << 14];
    sum += v;
    sq = fmaf(v, v, sq);
  }
  float mu = sum * (1.0f / DIMC);
  float var = sq * (1.0f / DIMC) - mu * mu;
  mu2[pg] = mu;
  rstd2[pg] = rsqrtf(var + 1e-5f);
}

// K6: ym = LN2(xf) @ w_p0 + b_p0 -> bf16 [b][f][p]
__global__ __launch_bounds__(256) void k6_p0(
    const float* __restrict__ xf, const float* __restrict__ mu2,
    const float* __restrict__ rstd2, const float* __restrict__ g,
    const float* __restrict__ bia, const float* __restrict__ wp0,
    const float* __restrict__ bp0, bfu* __restrict__ ym) {
  int pt = blockIdx.x, ft = blockIdx.y, b = blockIdx.z;
  __shared__ float As[128 * 64];
  __shared__ float Bs[128 * 64];
  int tid = threadIdx.x;
  for (int idx = tid; idx < 8192; idx += 256) {
    int c = idx >> 6, l = idx & 63;
    int p = pt * 64 + l;
    float v = xf[((size_t)(b * DIMC + c) << 14) + p];
    As[idx] = (v - mu2[(b << 14) + p]) * rstd2[(b << 14) + p] * g[c] + bia[c];
    Bs[idx] = wp0[c * HID + ft * 64 + l];
  }
  __syncthreads();
  int ti = tid & 15, tj = tid >> 4;
  float acc[4][4] = {};
  #pragma unroll 8
  for (int k = 0; k < 128; ++k) {
    float4 a = *(const float4*)&As[k * 64 + ti * 4];
    float4 bb = *(const float4*)&Bs[k * 64 + tj * 4];
    fma4x4(a, bb, acc);
  }
  #pragma unroll
  for (int jj = 0; jj < 4; ++jj) {
    int f = ft * 64 + tj * 4 + jj;
    float bo = bp0[f];
    ushort4 pk;
    pk.x = f2bf(acc[jj][0] + bo);
    pk.y = f2bf(acc[jj][1] + bo);
    pk.z = f2bf(acc[jj][2] + bo);
    pk.w = f2bf(acc[jj][3] + bo);
    *(ushort4*)&ym[((size_t)(b * HID + f) << 14) + pt * 64 + ti * 4] = pk;
  }
}

// K7: 5x5 depthwise conv, pad 2
__global__ __launch_bounds__(128) void k7_conv(
    const bfu* __restrict__ ym, const float* __restrict__ dwk,
    bfu* __restrict__ ym2) {
  int hh = blockIdx.x, f = blockIdx.y, b = blockIdx.z;
  int w = threadIdx.x;
  const bfu* in = ym + ((size_t)(b * HID + f) << 14);
  const float* wk = dwk + f * 25;
  float acc = 0.f;
  #pragma unroll
  for (int ky = 0; ky < 5; ++ky) {
    int y = hh + ky - 2;
    if (y < 0 || y >= 128) continue;
    #pragma unroll
    for (int kx = 0; kx < 5; ++kx) {
      int xx = w + kx - 2;
      if (xx < 0 || xx >= 128) continue;
      acc = fmaf(bf2f(in[y * 128 + xx]), wk[ky * 5 + kx], acc);
    }
  }
  ym2[((size_t)(b * HID + f) << 14) + hh * 128 + w] = f2bf(acc);
}

// K8: BN batch stats per channel
__global__ __launch_bounds__(256) void k8_bnstats(
    const bfu* __restrict__ ym2, float* __restrict__ bnm,
    float* __restrict__ bnr) {
  int f = blockIdx.x;
  int tid = threadIdx.x;
  float sum = 0.f, sq = 0.f;
  for (int b = 0; b < BB; ++b) {
    const bfu* p = ym2 + ((size_t)(b * HID + f) << 14);
    for (int idx = tid; idx < HW; idx += 256) {
      float v = bf2f(p[idx]);
      sum += v;
      sq = fmaf(v, v, sq);
    }
  }
  __shared__ float rs[256];
  __shared__ float rq[256];
  rs[tid] = sum;
  rq[tid] = sq;
  __syncthreads();
  for (int off = 128; off > 0; off >>= 1) {
    if (tid < off) {
      rs[tid] += rs[tid + off];
      rq[tid] += rq[tid + off];
    }
    __syncthreads();
  }
  if (tid == 0) {
    float mu = rs[0] * (1.0f / 65536.f);
    float var = rq[0] * (1.0f / 65536.f) - mu * mu;
    bnm[f] = mu;
    bnr[f] = rsqrtf(var + 1e-5f);
  }
}

// K9: g2 = gelu(gelu(bn(ym2)))
__global__ __launch_bounds__(256) void k9_act(
    const bfu* __restrict__ ym2, const float* __restrict__ bnm,
    const float* __restrict__ bnr, const float* __restrict__ g,
    const float* __restrict__ bia, bfu* __restrict__ g2) {
  int base = (blockIdx.x * 256 + threadIdx.x) * 4;
  int f = (base >> 14) & (HID - 1);
  float mean = bnm[f];
  float sc = bnr[f] * g[f];
  float bb = bia[f];
  ushort4 rv = *(const ushort4*)&ym2[base];
  float v0 = (bf2f(rv.x) - mean) * sc + bb;
  float v1 = (bf2f(rv.y) - mean) * sc + bb;
  float v2 = (bf2f(rv.z) - mean) * sc + bb;
  float v3 = (bf2f(rv.w) - mean) * sc + bb;
  v0 = gelu_exact(gelu_exact(v0));
  v1 = gelu_exact(gelu_exact(v1));
  v2 = gelu_exact(gelu_exact(v2));
  v3 = gelu_exact(gelu_exact(v3));
  ushort4 pk;
  pk.x = f2bf(v0);
  pk.y = f2bf(v1);
  pk.z = f2bf(v2);
  pk.w = f2bf(v3);
  *(ushort4*)&g2[base] = pk;
}

// K10: out = g2 @ w_p2 + b_p2 + xf
__global__ __launch_bounds__(256) void k10_p2(
    const bfu* __restrict__ g2, const float* __restrict__ wp2,
    const float* __restrict__ bp2, const float* __restrict__ xf,
    float* __restrict__ outp) {
  int pt = blockIdx.x, ct = blockIdx.y, b = blockIdx.z;
  __shared__ float As[128 * 64];
  __shared__ float Bs[128 * 64];
  int tid = threadIdx.x;
  int ti = tid & 15, tj = tid >> 4;
  float acc[4][4] = {};
  for (int kt = 0; kt < 2; ++kt) {
    for (int idx = tid; idx < 8192; idx += 256) {
      int k = idx >> 6, l = idx & 63;
      int f = kt * 128 + k;
      As[idx] = bf2f(g2[((size_t)(b * HID + f) << 14) + pt * 64 + l]);
      Bs[idx] = wp2[f * DIMC + ct * 64 + l];
    }
    __syncthreads();
    #pragma unroll 8
    for (int k = 0; k < 128; ++k) {
      float4 a = *(const float4*)&As[k * 64 + ti * 4];
      float4 bb = *(const float4*)&Bs[k * 64 + tj * 4];
      fma4x4(a, bb, acc);
    }
    __syncthreads();
  }
  #pragma unroll
  for (int jj = 0; jj < 4; ++jj) {
    int c = ct * 64 + tj * 4 + jj;
    float bo = bp2[c];
    size_t off = ((size_t)(b * DIMC + c) << 14) + pt * 64 + ti * 4;
    float4 res = *(const float4*)&xf[off];
    res.x += acc[jj][0] + bo;
    res.y += acc[jj][1] + bo;
    res.z += acc[jj][2] + bo;
    res.w += acc[jj][3] + bo;
    *(float4*)&outp[off] = res;
  }
}

extern "C" void kernel_launch(void* const* d_in, const int* in_sizes, int n_in,
                              void* d_out, int out_size, void* d_ws,
                              size_t ws_size, hipStream_t stream) {
  const float* x = (const float*)d_in[0];
  const float* ln1_g = (const float*)d_in[1];
  const float* ln1_b = (const float*)d_in[2];
  const float* w_qkv = (const float*)d_in[3];
  const float* w_out = (const float*)d_in[4];
  const float* b_out = (const float*)d_in[5];
  const float* ln2_g = (const float*)d_in[6];
  const float* ln2_b = (const float*)d_in[7];
  const float* w_p0 = (const float*)d_in[8];
  const float* b_p0 = (const float*)d_in[9];
  const float* dw_k = (const float*)d_in[10];
  const float* bn_g = (const float*)d_in[11];
  const float* bn_b = (const float*)d_in[12];
  const float* w_p2 = (const float*)d_in[13];
  const float* b_p2 = (const float*)d_in[14];
  float* outp = (float*)d_out;

  char* ws = (char*)d_ws;
  size_t off = 0;
  auto alloc = [&](size_t bytes) {
    void* p = ws + off;
    off += (bytes + 1023) & ~(size_t)1023;
    return p;
  };
  float* tok = (float*)alloc((size_t)NREG * DIMC * TT * 4);
  float* mu1 = (float*)alloc((size_t)NREG * TT * 4);
  float* rstd1 = (float*)alloc((size_t)NREG * TT * 4);
  bfu* qkvt = (bfu*)alloc((size_t)NREG * 384 * TT * 2);
  bfu* o = (bfu*)alloc((size_t)NREG * DIMC * TT * 2);
  float* xf = (float*)alloc((size_t)BB * DIMC * HW * 4);
  float* mu2 = (float*)alloc((size_t)BB * HW * 4);
  float* rstd2 = (float*)alloc((size_t)BB * HW * 4);
  bfu* ym = (bfu*)alloc((size_t)BB * HID * HW * 2);
  bfu* ym2 = (bfu*)alloc((size_t)BB * HID * HW * 2);
  float* bnm = (float*)alloc(HID * 4);
  float* bnr = (float*)alloc(HID * 4);

  k1_gather<<<NREG, 256, 0, stream>>>(x, tok, mu1, rstd1);
  k2_qkv<<<dim3(NREG, 24), 256, 0, stream>>>(tok, mu1, rstd1, ln1_g, ln1_b,
                                             w_qkv, qkvt);
  k3_attn<<<dim3(NREG, NHEADS), 256, 0, stream>>>(qkvt, o);
  k4_outproj<<<dim3(NREG, 8), 256, 0, stream>>>(o, w_out, b_out, tok);
  k5_merge<<<dim3(HH_, DIMC, BB), 128, 0, stream>>>(tok, xf);
  k5b_ln2stats<<<256, 256, 0, stream>>>(xf, mu2, rstd2);
  k6_p0<<<dim3(256, 4, BB), 256, 0, stream>>>(xf, mu2, rstd2, ln2_g, ln2_b,
                                              w_p0, b_p0, ym);
  k7_conv<<<dim3(HH_, HID, BB), 128, 0, stream>>>(ym, dw_k, ym2);
  k8_bnstats<<<HID, 256, 0, stream>>>(ym2, bnm, bnr);
  k9_act<<<16384, 256, 0, stream>>>(ym2, bnm, bnr, bn_g, bn_b, ym);
  k10_p2<<<dim3(256, 2, BB), 256, 0, stream>>>(ym, w_p2, b_p2, xf, outp);
}

// Round 3
// 577.078 us; speedup vs baseline: 2.0329x; 1.5079x over previous
//
#include <hip/hip_runtime.h>

#define DIMC 128
#define NHEADS 4
#define HD 32
#define HID 256
#define BB 4
#define HH_ 128
#define WW_ 128
#define HW 16384
#define RS 16
#define STEP 14
#define NR 9
#define NREGB 81
#define NREG 324
#define TT 256

typedef unsigned short bfu;  // bf16 bits
typedef __attribute__((ext_vector_type(8))) short bf16x8;
typedef __attribute__((ext_vector_type(4))) float f32x4;

__device__ __forceinline__ float bf2f(bfu u) {
  return __uint_as_float(((unsigned int)u) << 16);
}
__device__ __forceinline__ bfu f2bf(float f) {
  unsigned int i = __float_as_uint(f);
  unsigned int r = i + 0x7fffu + ((i >> 16) & 1u);
  return (bfu)(r >> 16);
}
__device__ __forceinline__ float gelu_exact(float x) {
  return 0.5f * x * (1.0f + erff(x * 0.70710678118654752f));
}
__device__ __forceinline__ void fma4x4(const float4 a, const float4 b, float acc[4][4]) {
  acc[0][0] = fmaf(b.x, a.x, acc[0][0]);
  acc[0][1] = fmaf(b.x, a.y, acc[0][1]);
  acc[0][2] = fmaf(b.x, a.z, acc[0][2]);
  acc[0][3] = fmaf(b.x, a.w, acc[0][3]);
  acc[1][0] = fmaf(b.y, a.x, acc[1][0]);
  acc[1][1] = fmaf(b.y, a.y, acc[1][1]);
  acc[1][2] = fmaf(b.y, a.z, acc[1][2]);
  acc[1][3] = fmaf(b.y, a.w, acc[1][3]);
  acc[2][0] = fmaf(b.z, a.x, acc[2][0]);
  acc[2][1] = fmaf(b.z, a.y, acc[2][1]);
  acc[2][2] = fmaf(b.z, a.z, acc[2][2]);
  acc[2][3] = fmaf(b.z, a.w, acc[2][3]);
  acc[3][0] = fmaf(b.w, a.x, acc[3][0]);
  acc[3][1] = fmaf(b.w, a.y, acc[3][1]);
  acc[3][2] = fmaf(b.w, a.z, acc[3][2]);
  acc[3][3] = fmaf(b.w, a.w, acc[3][3]);
}

// K1: gather -> tok fp32 [reg][c][t]; also LN1'd bf16 aln [reg][c][t]
__global__ __launch_bounds__(256) void k1_gather(
    const float* __restrict__ x, const float* __restrict__ g,
    const float* __restrict__ bia, float* __restrict__ tok,
    bfu* __restrict__ aln) {
  int reg = blockIdx.x;
  int b = reg / NREGB, ij = reg % NREGB;
  int i = ij / NR, j = ij % NR;
  int t = threadIdx.x;
  int r = t >> 4, s = t & 15;
  int hh = i * STEP + r, ww = j * STEP + s;
  const float* xp = x + (size_t)b * DIMC * HW + (size_t)hh * WW_ + ww;
  float* tp = tok + (size_t)reg * DIMC * TT + t;
  float sum = 0.f, sq = 0.f;
  #pragma unroll 4
  for (int c = 0; c < DIMC; ++c) {
    float v = xp[(size_t)c * HW];
    tp[c * TT] = v;
    sum += v;
    sq = fmaf(v, v, sq);
  }
  float mu = sum * (1.0f / DIMC);
  float var = sq * (1.0f / DIMC) - mu * mu;
  float rstd = rsqrtf(var + 1e-5f);
  bfu* ap = aln + (size_t)reg * DIMC * TT + t;
  #pragma unroll 4
  for (int c = 0; c < DIMC; ++c) {
    float v = xp[(size_t)c * HW];  // L2-hot re-read
    ap[c * TT] = f2bf((v - mu) * rstd * g[c] + bia[c]);
  }
}

// K2: MFMA qkv GEMM. Block = (region, mt of 64 tokens), 4 waves.
// C[64 x 384] = aln[64 x 128] @ w_qkv[128 x 384], K in 4 phases of 32.
__global__ __launch_bounds__(256) void k2_qkv(
    const bfu* __restrict__ aln, const float* __restrict__ wqkv,
    bfu* __restrict__ qkvt) {
  int reg = blockIdx.x;
  int mt = blockIdx.y;
  __shared__ __align__(16) bfu sA[64 * 40];   // [t][k]
  __shared__ __align__(16) bfu sB[384 * 40];  // [n][k]
  int tid = threadIdx.x;
  int wave = tid >> 6, lane = tid & 63;
  int quad = lane >> 4, n16 = lane & 15;
  const bfu* alr = aln + (size_t)reg * DIMC * TT;
  f32x4 acc[24];
  #pragma unroll
  for (int nt = 0; nt < 24; ++nt) acc[nt] = (f32x4){0.f, 0.f, 0.f, 0.f};
  for (int ph = 0; ph < 4; ++ph) {
    for (int idx = tid; idx < 2048; idx += 256) {
      int t = idx & 63, k = idx >> 6;
      sA[t * 40 + k] = alr[(ph * 32 + k) * TT + mt * 64 + t];
    }
    for (int idx = tid; idx < 12288; idx += 256) {
      int n = idx % 384, k = idx / 384;
      sB[n * 40 + k] = f2bf(wqkv[(ph * 32 + k) * 384 + n]);
    }
    __syncthreads();
    bf16x8 af = *(const bf16x8*)&sA[(wave * 16 + n16) * 40 + quad * 8];
    #pragma unroll
    for (int nt = 0; nt < 24; ++nt) {
      bf16x8 bfr = *(const bf16x8*)&sB[(nt * 16 + n16) * 40 + quad * 8];
      acc[nt] = __builtin_amdgcn_mfma_f32_16x16x32_bf16(af, bfr, acc[nt], 0, 0, 0);
    }
    __syncthreads();
  }
  bfu* outp = qkvt + ((size_t)reg * 256 + mt * 64 + wave * 16 + quad * 4) * 384;
  #pragma unroll
  for (int nt = 0; nt < 24; ++nt)
    #pragma unroll
    for (int r = 0; r < 4; ++r)
      outp[r * 384 + nt * 16 + n16] = f2bf(acc[nt][r]);
}

// K3: MFMA attention (unchanged from R1)
__global__ __launch_bounds__(256, 2) void k3_attn(
    const bfu* __restrict__ qkvt, bfu* __restrict__ o) {
  int reg = blockIdx.x;
  int h = blockIdx.y;
  __shared__ __align__(16) bfu sVt[32 * 264];
  __shared__ __align__(16) bfu sP[4][16 * 264];
  int tid = threadIdx.x;
  int wave = tid >> 6, lane = tid & 63;
  int quad = lane >> 4, n16 = lane & 15;
  const bfu* qb = qkvt + (size_t)reg * 256 * 384;
  {
    const bfu* vrow = qb + tid * 384 + 256 + h * 32;
    #pragma unroll
    for (int dg = 0; dg < 8; ++dg) {
      ushort4 v4 = *(const ushort4*)(vrow + dg * 4);
      sVt[(dg * 4 + 0) * 264 + tid] = v4.x;
      sVt[(dg * 4 + 1) * 264 + tid] = v4.y;
      sVt[(dg * 4 + 2) * 264 + tid] = v4.z;
      sVt[(dg * 4 + 3) * 264 + tid] = v4.w;
    }
  }
  __syncthreads();
  bf16x8 vf[2][8];
  #pragma unroll
  for (int nt = 0; nt < 2; ++nt)
    #pragma unroll
    for (int kt = 0; kt < 8; ++kt)
      vf[nt][kt] = *(const bf16x8*)&sVt[(nt * 16 + n16) * 264 + kt * 32 + quad * 8];
  const bfu* kptr = qb + n16 * 384 + 128 + h * 32 + quad * 8;
  const f32x4 zero = {0.f, 0.f, 0.f, 0.f};
  const float scale = 0.17677669529663687f;
  bfu* pw = sP[wave];
  for (int mi = 0; mi < 4; ++mi) {
    int mt = wave * 4 + mi;
    bf16x8 qf = *(const bf16x8*)(qb + (mt * 16 + n16) * 384 + h * 32 + quad * 8);
    f32x4 st[16];
    #pragma unroll
    for (int T = 0; T < 16; ++T) {
      bf16x8 kf = *(const bf16x8*)(kptr + T * 16 * 384);
      st[T] = __builtin_amdgcn_mfma_f32_16x16x32_bf16(qf, kf, zero, 0, 0, 0);
    }
    float inv[4];
    #pragma unroll
    for (int r = 0; r < 4; ++r) {
      float m = st[0][r];
      #pragma unroll
      for (int T = 1; T < 16; ++T) m = fmaxf(m, st[T][r]);
      #pragma unroll
      for (int mk = 1; mk < 16; mk <<= 1) m = fmaxf(m, __shfl_xor(m, mk, 64));
      float l = 0.f;
      #pragma unroll
      for (int T = 0; T < 16; ++T) {
        float p = __expf((st[T][r] - m) * scale);
        st[T][r] = p;
        l += p;
      }
      #pragma unroll
      for (int mk = 1; mk < 16; mk <<= 1) l += __shfl_xor(l, mk, 64);
      inv[r] = 1.0f / l;
    }
    #pragma unroll
    for (int T = 0; T < 16; ++T) {
      #pragma unroll
      for (int r = 0; r < 4; ++r)
        pw[(quad * 4 + r) * 264 + T * 16 + n16] = f2bf(st[T][r]);
    }
    __builtin_amdgcn_wave_barrier();
    f32x4 oa0 = zero, oa1 = zero;
    #pragma unroll
    for (int kt = 0; kt < 8; ++kt) {
      bf16x8 pf = *(const bf16x8*)&pw[n16 * 264 + kt * 32 + quad * 8];
      oa0 = __builtin_amdgcn_mfma_f32_16x16x32_bf16(pf, vf[0][kt], oa0, 0, 0, 0);
      oa1 = __builtin_amdgcn_mfma_f32_16x16x32_bf16(pf, vf[1][kt], oa1, 0, 0, 0);
    }
    __builtin_amdgcn_wave_barrier();
    bfu* ob = o + ((size_t)reg * 256 + mt * 16 + quad * 4) * 128 + h * 32 + n16;
    #pragma unroll
    for (int r = 0; r < 4; ++r) {
      ob[r * 128] = f2bf(oa0[r] * inv[r]);
      ob[r * 128 + 16] = f2bf(oa1[r] * inv[r]);
    }
  }
}

// K4: tok[c][t] += o @ w_out + b_out (o token-major, LDS transpose)
__global__ __launch_bounds__(256) void k4_outproj(
    const bfu* __restrict__ o, const float* __restrict__ wout,
    const float* __restrict__ bout, float* __restrict__ tok) {
  int reg = blockIdx.x;
  int ct = blockIdx.y >> 2, tt = blockIdx.y & 3;
  __shared__ float As[128 * 64];
  __shared__ float Bs[64 * 68];
  int tid = threadIdx.x;
  for (int idx = tid; idx < 8192; idx += 256) {
    int k = idx >> 6, l = idx & 63;
    As[idx] = wout[k * 128 + ct * 64 + l];
  }
  int ti = tid & 15, tj = tid >> 4;
  float acc[4][4] = {};
  const bfu* ob = o + (size_t)reg * 256 * 128;
  for (int ph = 0; ph < 2; ++ph) {
    __syncthreads();
    for (int idx = tid; idx < 4096; idx += 256) {
      int l = idx >> 6, k = idx & 63;
      Bs[k * 68 + l] = bf2f(ob[(tt * 64 + l) * 128 + ph * 64 + k]);
    }
    __syncthreads();
    #pragma unroll 8
    for (int k = 0; k < 64; ++k) {
      float4 a = *(const float4*)&Bs[k * 68 + ti * 4];
      float4 bb = *(const float4*)&As[(ph * 64 + k) * 64 + tj * 4];
      fma4x4(a, bb, acc);
    }
  }
  float* tokr = tok + (size_t)reg * DIMC * TT;
  #pragma unroll
  for (int jj = 0; jj < 4; ++jj) {
    int c = ct * 64 + tj * 4 + jj;
    float bo = bout[c];
    float4 res = *(const float4*)&tokr[c * TT + tt * 64 + ti * 4];
    res.x += acc[jj][0] + bo;
    res.y += acc[jj][1] + bo;
    res.z += acc[jj][2] + bo;
    res.w += acc[jj][3] + bo;
    *(float4*)&tokr[c * TT + tt * 64 + ti * 4] = res;
  }
}

// K5: overlap-average merge -> xf NCHW
__global__ __launch_bounds__(128) void k5_merge(
    const float* __restrict__ tok, float* __restrict__ xf) {
  int hh = blockIdx.x, c = blockIdx.y, b = blockIdx.z;
  int w = threadIdx.x;
  int ilo = (hh >= 2) ? (hh - 2) / 14 : 0;
  int ihi = hh / 14;
  if (ihi > 8) ihi = 8;
  int jlo = (w >= 2) ? (w - 2) / 14 : 0;
  int jhi = w / 14;
  if (jhi > 8) jhi = 8;
  float sum = 0.f;
  for (int i = ilo; i <= ihi; ++i)
    for (int j = jlo; j <= jhi; ++j) {
      int reg = b * NREGB + i * NR + j;
      int r = hh - i * STEP, s = w - j * STEP;
      sum += tok[(size_t)reg * DIMC * TT + c * TT + r * 16 + s];
    }
  float cnt = (float)((ihi - ilo + 1) * (jhi - jlo + 1));
  xf[((size_t)(b * DIMC + c) << 14) + hh * WW_ + w] = sum / cnt;
}

// K5b: LN2 per-pixel stats
__global__ __launch_bounds__(256) void k5b_ln2stats(
    const float* __restrict__ xf, float* __restrict__ mu2,
    float* __restrict__ rstd2) {
  int pg = blockIdx.x * 256 + threadIdx.x;
  int b = pg >> 14, p = pg & 16383;
  const float* xp = xf + ((size_t)b * DIMC << 14) + p;
  float sum = 0.f, sq = 0.f;
  #pragma unroll 4
  for (int c = 0; c < DIMC; ++c) {
    float v = xp[(size_t)c << 14];
    sum += v;
    sq = fmaf(v, v, sq);
  }
  float mu = sum * (1.0f / DIMC);
  float var = sq * (1.0f / DIMC) - mu * mu;
  mu2[pg] = mu;
  rstd2[pg] = rsqrtf(var + 1e-5f);
}

// K6: ym = LN2(xf) @ w_p0 + b_p0 -> bf16 [b][f][p]
__global__ __launch_bounds__(256) void k6_p0(
    const float* __restrict__ xf, const float* __restrict__ mu2,
    const float* __restrict__ rstd2, const float* __restrict__ g,
    const float* __restrict__ bia, const float* __restrict__ wp0,
    const float* __restrict__ bp0, bfu* __restrict__ ym) {
  int pt = blockIdx.x, ft = blockIdx.y, b = blockIdx.z;
  __shared__ float As[128 * 64];
  __shared__ float Bs[128 * 64];
  int tid = threadIdx.x;
  for (int idx = tid; idx < 8192; idx += 256) {
    int c = idx >> 6, l = idx & 63;
    int p = pt * 64 + l;
    float v = xf[((size_t)(b * DIMC + c) << 14) + p];
    As[idx] = (v - mu2[(b << 14) + p]) * rstd2[(b << 14) + p] * g[c] + bia[c];
    Bs[idx] = wp0[c * HID + ft * 64 + l];
  }
  __syncthreads();
  int ti = tid & 15, tj = tid >> 4;
  float acc[4][4] = {};
  #pragma unroll 8
  for (int k = 0; k < 128; ++k) {
    float4 a = *(const float4*)&As[k * 64 + ti * 4];
    float4 bb = *(const float4*)&Bs[k * 64 + tj * 4];
    fma4x4(a, bb, acc);
  }
  #pragma unroll
  for (int jj = 0; jj < 4; ++jj) {
    int f = ft * 64 + tj * 4 + jj;
    float bo = bp0[f];
    ushort4 pk;
    pk.x = f2bf(acc[jj][0] + bo);
    pk.y = f2bf(acc[jj][1] + bo);
    pk.z = f2bf(acc[jj][2] + bo);
    pk.w = f2bf(acc[jj][3] + bo);
    *(ushort4*)&ym[((size_t)(b * HID + f) << 14) + pt * 64 + ti * 4] = pk;
  }
}

// zero-init 512 floats (bn accumulators)
__global__ void kz(float* __restrict__ p) {
  p[blockIdx.x * 256 + threadIdx.x] = 0.f;
}

// K7: 5x5 depthwise conv, whole plane in LDS (stride 134), fused BN partials
__global__ __launch_bounds__(256) void k7_conv(
    const bfu* __restrict__ ym, const float* __restrict__ dwk,
    bfu* __restrict__ ym2, float* __restrict__ bnacc) {
  int bf = blockIdx.x;  // b*HID + f
  int f = bf & (HID - 1);
  __shared__ bfu sp[128 * 134];  // 34.3 KB
  const bfu* in = ym + ((size_t)bf << 14);
  int tid = threadIdx.x;
  for (int idx = tid; idx < 2048; idx += 256) {
    int r = idx >> 4, c8 = (idx & 15) << 3;
    ushort4 a = *(const ushort4*)&in[(r << 7) + c8];
    ushort4 b = *(const ushort4*)&in[(r << 7) + c8 + 4];
    bfu* d = &sp[r * 134 + c8];
    d[0] = a.x; d[1] = a.y; d[2] = a.z; d[3] = a.w;
    d[4] = b.x; d[5] = b.y; d[6] = b.z; d[7] = b.w;
  }
  float wk[25];
  #pragma unroll
  for (int i = 0; i < 25; ++i) wk[i] = dwk[f * 25 + i];
  __syncthreads();
  int row = tid >> 1, half = (tid & 1) << 6;
  float acc[64];
  #pragma unroll
  for (int i = 0; i < 64; ++i) acc[i] = 0.f;
  #pragma unroll
  for (int ky = 0; ky < 5; ++ky) {
    int y = row + ky - 2;
    if (y < 0 || y >= 128) continue;
    const bfu* rp = &sp[y * 134];
    float win[68];
    #pragma unroll
    for (int c = 0; c < 68; ++c) {
      int cc = half + c - 2;
      win[c] = (cc >= 0 && cc < 128) ? bf2f(rp[cc]) : 0.f;
    }
    #pragma unroll
    for (int kx = 0; kx < 5; ++kx) {
      float wv = wk[ky * 5 + kx];
      #pragma unroll
      for (int i = 0; i < 64; ++i) acc[i] = fmaf(win[i + kx], wv, acc[i]);
    }
  }
  float s = 0.f, sq = 0.f;
  #pragma unroll
  for (int i = 0; i < 64; ++i) {
    s += acc[i];
    sq = fmaf(acc[i], acc[i], sq);
  }
  bfu* op = ym2 + ((size_t)bf << 14) + (row << 7) + half;
  #pragma unroll
  for (int g8 = 0; g8 < 8; ++g8) {
    bfu tmp[8];
    #pragma unroll
    for (int i = 0; i < 8; ++i) tmp[i] = f2bf(acc[g8 * 8 + i]);
    *(uint4*)&op[g8 * 8] = *(const uint4*)tmp;
  }
  __syncthreads();
  float* red = (float*)sp;
  red[tid] = s;
  red[256 + tid] = sq;
  __syncthreads();
  for (int o = 128; o > 0; o >>= 1) {
    if (tid < o) {
      red[tid] += red[tid + o];
      red[256 + tid] += red[256 + tid + o];
    }
    __syncthreads();
  }
  if (tid == 0) {
    atomicAdd(&bnacc[f], red[0]);
    atomicAdd(&bnacc[HID + f], red[256]);
  }
}

// K8: finalize BN stats
__global__ __launch_bounds__(256) void k8_fin(
    const float* __restrict__ bnacc, float* __restrict__ bnm,
    float* __restrict__ bnr) {
  int f = threadIdx.x;
  float mu = bnacc[f] * (1.0f / 65536.f);
  float var = bnacc[HID + f] * (1.0f / 65536.f) - mu * mu;
  bnm[f] = mu;
  bnr[f] = rsqrtf(var + 1e-5f);
}

// K9: g2 = gelu(gelu(bn(ym2)))
__global__ __launch_bounds__(256) void k9_act(
    const bfu* __restrict__ ym2, const float* __restrict__ bnm,
    const float* __restrict__ bnr, const float* __restrict__ g,
    const float* __restrict__ bia, bfu* __restrict__ g2) {
  int base = (blockIdx.x * 256 + threadIdx.x) * 4;
  int f = (base >> 14) & (HID - 1);
  float mean = bnm[f];
  float sc = bnr[f] * g[f];
  float bb = bia[f];
  ushort4 rv = *(const ushort4*)&ym2[base];
  float v0 = (bf2f(rv.x) - mean) * sc + bb;
  float v1 = (bf2f(rv.y) - mean) * sc + bb;
  float v2 = (bf2f(rv.z) - mean) * sc + bb;
  float v3 = (bf2f(rv.w) - mean) * sc + bb;
  v0 = gelu_exact(gelu_exact(v0));
  v1 = gelu_exact(gelu_exact(v1));
  v2 = gelu_exact(gelu_exact(v2));
  v3 = gelu_exact(gelu_exact(v3));
  ushort4 pk;
  pk.x = f2bf(v0);
  pk.y = f2bf(v1);
  pk.z = f2bf(v2);
  pk.w = f2bf(v3);
  *(ushort4*)&g2[base] = pk;
}

// K10: out = g2 @ w_p2 + b_p2 + xf
__global__ __launch_bounds__(256) void k10_p2(
    const bfu* __restrict__ g2, const float* __restrict__ wp2,
    const float* __restrict__ bp2, const float* __restrict__ xf,
    float* __restrict__ outp) {
  int pt = blockIdx.x, ct = blockIdx.y, b = blockIdx.z;
  __shared__ float As[128 * 64];
  __shared__ float Bs[128 * 64];
  int tid = threadIdx.x;
  int ti = tid & 15, tj = tid >> 4;
  float acc[4][4] = {};
  for (int kt = 0; kt < 2; ++kt) {
    for (int idx = tid; idx < 8192; idx += 256) {
      int k = idx >> 6, l = idx & 63;
      int f = kt * 128 + k;
      As[idx] = bf2f(g2[((size_t)(b * HID + f) << 14) + pt * 64 + l]);
      Bs[idx] = wp2[f * DIMC + ct * 64 + l];
    }
    __syncthreads();
    #pragma unroll 8
    for (int k = 0; k < 128; ++k) {
      float4 a = *(const float4*)&As[k * 64 + ti * 4];
      float4 bb = *(const float4*)&Bs[k * 64 + tj * 4];
      fma4x4(a, bb, acc);
    }
    __syncthreads();
  }
  #pragma unroll
  for (int jj = 0; jj < 4; ++jj) {
    int c = ct * 64 + tj * 4 + jj;
    float bo = bp2[c];
    size_t off = ((size_t)(b * DIMC + c) << 14) + pt * 64 + ti * 4;
    float4 res = *(const float4*)&xf[off];
    res.x += acc[jj][0] + bo;
    res.y += acc[jj][1] + bo;
    res.z += acc[jj][2] + bo;
    res.w += acc[jj][3] + bo;
    *(float4*)&outp[off] = res;
  }
}

extern "C" void kernel_launch(void* const* d_in, const int* in_sizes, int n_in,
                              void* d_out, int out_size, void* d_ws,
                              size_t ws_size, hipStream_t stream) {
  const float* x = (const float*)d_in[0];
  const float* ln1_g = (const float*)d_in[1];
  const float* ln1_b = (const float*)d_in[2];
  const float* w_qkv = (const float*)d_in[3];
  const float* w_out = (const float*)d_in[4];
  const float* b_out = (const float*)d_in[5];
  const float* ln2_g = (const float*)d_in[6];
  const float* ln2_b = (const float*)d_in[7];
  const float* w_p0 = (const float*)d_in[8];
  const float* b_p0 = (const float*)d_in[9];
  const float* dw_k = (const float*)d_in[10];
  const float* bn_g = (const float*)d_in[11];
  const float* bn_b = (const float*)d_in[12];
  const float* w_p2 = (const float*)d_in[13];
  const float* b_p2 = (const float*)d_in[14];
  float* outp = (float*)d_out;

  char* ws = (char*)d_ws;
  size_t off = 0;
  auto alloc = [&](size_t bytes) {
    void* p = ws + off;
    off += (bytes + 1023) & ~(size_t)1023;
    return p;
  };
  float* tok = (float*)alloc((size_t)NREG * DIMC * TT * 4);    // 85 MB
  bfu* qkvt = (bfu*)alloc((size_t)NREG * 384 * TT * 2);        // 63.7 MB
  float* xf = (float*)alloc((size_t)BB * DIMC * HW * 4);       // 33.5 MB
  float* mu2 = (float*)alloc((size_t)BB * HW * 4);
  float* rstd2 = (float*)alloc((size_t)BB * HW * 4);
  bfu* ym = (bfu*)alloc((size_t)BB * HID * HW * 2);            // 33.5 MB
  bfu* ym2 = (bfu*)alloc((size_t)BB * HID * HW * 2);           // 33.5 MB
  float* bnacc = (float*)alloc(2 * HID * 4);
  float* bnm = (float*)alloc(HID * 4);
  float* bnr = (float*)alloc(HID * 4);
  // overlays (lifetimes disjoint): o lives in ym region; aln in ym2 region
  bfu* o = ym;     // used k3->k4; ym written first in k6
  bfu* aln = ym2;  // used k1->k2; ym2 written first in k7

  k1_gather<<<NREG, 256, 0, stream>>>(x, ln1_g, ln1_b, tok, aln);
  k2_qkv<<<dim3(NREG, 4), 256, 0, stream>>>(aln, w_qkv, qkvt);
  k3_attn<<<dim3(NREG, NHEADS), 256, 0, stream>>>(qkvt, o);
  k4_outproj<<<dim3(NREG, 8), 256, 0, stream>>>(o, w_out, b_out, tok);
  k5_merge<<<dim3(HH_, DIMC, BB), 128, 0, stream>>>(tok, xf);
  k5b_ln2stats<<<256, 256, 0, stream>>>(xf, mu2, rstd2);
  k6_p0<<<dim3(256, 4, BB), 256, 0, stream>>>(xf, mu2, rstd2, ln2_g, ln2_b,
                                              w_p0, b_p0, ym);
  kz<<<2, 256, 0, stream>>>(bnacc);
  k7_conv<<<BB * HID, 256, 0, stream>>>(ym, dw_k, ym2, bnacc);
  k8_fin<<<1, 256, 0, stream>>>(bnacc, bnm, bnr);
  k9_act<<<16384, 256, 0, stream>>>(ym2, bnm, bnr, bn_g, bn_b, ym);
  k10_p2<<<dim3(256, 2, BB), 256, 0, stream>>>(ym, w_p2, b_p2, xf, outp);
}